// Round 10
// baseline (241.755 us; speedup 1.0000x reference)
//
#include <hip/hip_runtime.h>
#include <hip/hip_bf16.h>
#include <stdint.h>

// ---------------- problem constants ----------------
#define N_NODES 16384
#define D_IN    256
#define D_OUT   256
#define K_SAMP  10
#define HALF_FLAT (1u << 27)

#define NPB 16          // nodes per block
#define NPW 4           // nodes per wave (4 waves/block)

// JAX PRNG mode: 1 = jax_threefry_partitionable (verified correct R3-R9).
#define JAX_PARTITIONABLE 1

typedef __attribute__((ext_vector_type(4))) float  f32x4;
typedef __attribute__((ext_vector_type(8))) short  bf16x8;
typedef __attribute__((ext_vector_type(4))) int    i32x4;

__device__ __forceinline__ uint32_t rotl32(uint32_t x, int r) {
    return (x << r) | (x >> (32 - r));
}

// Exact replica of jax threefry2x32 noise bits for flat index i = r*16384 + c, key (0,42).
__device__ __forceinline__ uint32_t jax_noise_bits(uint32_t r, uint32_t c) {
    const uint32_t i  = (r << 14) | c;
    const uint32_t k0 = 0u, k1 = 42u;
    const uint32_t k2 = 42u ^ 0x1BD11BDAu;
    uint32_t x0, x1;
#if JAX_PARTITIONABLE
    x0 = 0u;
    x1 = i;
#else
    const bool lo = (i < HALF_FLAT);
    x0 = lo ? i : (i - HALF_FLAT);
    x1 = lo ? (i + HALF_FLAT) : i;
#endif
    x0 += k0; x1 += k1;
#define TFR4(a,b,cc,d) \
    x0 += x1; x1 = rotl32(x1,a);  x1 ^= x0; \
    x0 += x1; x1 = rotl32(x1,b);  x1 ^= x0; \
    x0 += x1; x1 = rotl32(x1,cc); x1 ^= x0; \
    x0 += x1; x1 = rotl32(x1,d);  x1 ^= x0;
    TFR4(13,15,26,6);   x0 += k1; x1 += k2 + 1u;
    TFR4(17,29,16,24);  x0 += k2; x1 += k0 + 2u;
    TFR4(13,15,26,6);   x0 += k0; x1 += k1 + 3u;
    TFR4(17,29,16,24);  x0 += k1; x1 += k2 + 4u;
    TFR4(13,15,26,6);   x0 += k2; x1 += k0 + 5u;
#undef TFR4
#if JAX_PARTITIONABLE
    return x0 ^ x1;
#else
    return (i < HALF_FLAT) ? x0 : x1;
#endif
}

__device__ __forceinline__ unsigned short f2bfbits(float f) {
    __hip_bfloat16 h = __float2bfloat16(f);
    return *(unsigned short*)&h;
}

// ---------------- kernel W: convert W (f32 [256][512]) → Wb bf16 ----------------
// Separate kernel so Wb is globally visible before k_fused (kernel boundary = fence).
__global__ __launch_bounds__(256) void k_convw(const float* __restrict__ W,
                                               unsigned short* __restrict__ Wb)
{
    int i = (blockIdx.x * 256 + threadIdx.x) * 4;
    f32x4 v = *(const f32x4*)(W + i);
    ushort4 u;
    u.x = f2bfbits(v[0]); u.y = f2bfbits(v[1]);
    u.z = f2bfbits(v[2]); u.w = f2bfbits(v[3]);
    *(ushort4*)(Wb + i) = u;
}

// ---------------- fused kernel: sample+aggregate (h in LDS) + MFMA GEMM + relu ----------
// 1024 blocks x 256 threads (4 waves). Block owns 16 nodes; wave owns 4 (sequential).
// Phase A (per wave, no barriers — R8-verified sampling): nt-stream adjacency row,
//   ballot-compact nonzero cols, dense threefry, register top-10 with inline gathers,
//   write h row (bf16, XOR-swizzled) into LDS hS.
// Phase B (one __syncthreads): GEMM M=16,N=256,K=512. A = hS (LDS), B = Wb read
//   DIRECTLY from global (L2-resident 256 KB, reused 64x/block — no LDS staging, which
//   is what killed R9's occupancy). Bias+ReLU, nt f32 store.
// LDS = 16KB hS + 1KB candc → ~8 blocks/CU streaming occupancy (R8 level).
__global__ __launch_bounds__(256) void k_fused(
    const float* __restrict__ x, const float* __restrict__ adj,
    const unsigned short* __restrict__ Wb, const float* __restrict__ bias,
    float* __restrict__ out)
{
    __shared__ short hS[NPB * 512];                // 16 KB h tile, rows XOR-swizzled
    __shared__ unsigned short candc[4][128];       // 1 KB per-wave candidate lists

    const int t    = threadIdx.x;
    const int lane = t & 63;
    const int w    = t >> 6;

    // ================= Phase A: sampling (R8-verified logic) =================
    for (int i = 0; i < NPW; ++i) {
        const int lrow = w * NPW + i;                  // 0..15
        const int r    = blockIdx.x * NPB + lrow;

        // ---- stream + compact (nt loads, integer fast path: adj is exactly 0.0/1.0) ----
        const i32x4* rowp = (const i32x4*)(adj + (size_t)r * N_NODES);
        int nc = 0;                                    // wave-uniform candidate count
        #pragma unroll 8
        for (int it = 0; it < 64; ++it) {
            i32x4 v = __builtin_nontemporal_load(rowp + it * 64 + lane);
            uint32_t any = (uint32_t)v[0] | (uint32_t)v[1] | (uint32_t)v[2] | (uint32_t)v[3];
            if (__ballot(any != 0u)) {
                int cb = (it * 64 + lane) * 4;
                #pragma unroll
                for (int j = 0; j < 4; ++j) {
                    unsigned long long mask = __ballot(v[j] != 0);
                    if (mask) {
                        if (v[j] != 0) {
                            int below = __builtin_amdgcn_mbcnt_hi(
                                (uint32_t)(mask >> 32),
                                __builtin_amdgcn_mbcnt_lo((uint32_t)mask, 0));
                            int slot = nc + below;
                            if (slot < 128) candc[w][slot] = (unsigned short)(cb + j);
                        }
                        nc += __popcll(mask);
                    }
                }
            }
        }
        if (nc > 128) nc = 128;                        // P(deg>128) ~ 0 (17 sigma)

        // ---- dense threefry: keys for candidates lane and lane+64 ----
        // (within-wave ds_write->ds_read ordering via lgkmcnt; no barrier — R9-verified)
        unsigned long long k0 = 0ull, k1 = 0ull;
        if (lane < nc) {
            uint32_t c   = candc[w][lane];
            uint32_t u23 = jax_noise_bits((uint32_t)r, c) >> 9;  // monotone with uniform
            k0 = ((((unsigned long long)u23) << 14) | (unsigned long long)(16383u - c)) + 1ull;
        }
        if (64 + lane < nc) {
            uint32_t c   = candc[w][64 + lane];
            uint32_t u23 = jax_noise_bits((uint32_t)r, c) >> 9;
            k1 = ((((unsigned long long)u23) << 14) | (unsigned long long)(16383u - c)) + 1ull;
        }

        // ---- top-K selection (register space) + inline gathers ----
        const int m = nc < K_SAMP ? nc : K_SAMP;
        f32x4 acc = {0.f, 0.f, 0.f, 0.f};
        for (int s = 0; s < m; ++s) {
            unsigned long long my = k0 > k1 ? k0 : k1;
            #pragma unroll
            for (int o = 1; o < 64; o <<= 1) {
                unsigned long long other = __shfl_xor(my, o);
                if (other > my) my = other;
            }
            // keys unique (low 14 bits = distinct column) -> exactly one lane/slot matches
            if (k0 == my) k0 = 0ull; else if (k1 == my) k1 = 0ull;
            const int col = 16383 - (int)((my - 1ull) & 0x3FFFull);
            f32x4 xv = *(const f32x4*)(x + (size_t)col * D_IN + lane * 4);
            acc += xv;
        }
        const float inv = (m > 0) ? 1.0f / (float)m : 0.0f;

        // ---- write h row (bf16) into LDS, swizzled: byte ^= (row&7)<<4 (R9-verified) ----
        f32x4 sv = *(const f32x4*)(x + (size_t)r * D_IN + lane * 4);
        ushort4 us, ua;
        us.x = f2bfbits(sv[0]);        us.y = f2bfbits(sv[1]);
        us.z = f2bfbits(sv[2]);        us.w = f2bfbits(sv[3]);
        ua.x = f2bfbits(acc[0] * inv); ua.y = f2bfbits(acc[1] * inv);
        ua.z = f2bfbits(acc[2] * inv); ua.w = f2bfbits(acc[3] * inv);
        const int swz = (lrow & 7) << 4;
        *(ushort4*)((char*)hS + ((lrow * 1024 + lane * 8) ^ swz))       = us;   // self
        *(ushort4*)((char*)hS + ((lrow * 1024 + 512 + lane * 8) ^ swz)) = ua;   // agg
    }

    __syncthreads();   // h tile complete

    // ================= Phase B: GEMM M=16, N=256, K=512 =================
    // wave w owns cols wn*64..+63 (wn = w); all waves cover the same 16 rows.
    const int wn = w;              // 0..3
    const int lr = lane & 15;
    const int lk = lane >> 4;

    f32x4 acc[4] = {};             // 4 n-frags

    #pragma unroll 4
    for (int kk = 0; kk < 512; kk += 32) {
        // A fragment from hS: row = lr; byte = row*1024 + kk*2 + lk*16, XOR swizzle
        const int aba = (lr * 1024 + kk * 2 + lk * 16) ^ ((lr & 7) << 4);
        bf16x8 af = *(const bf16x8*)((const char*)hS + aba);
        #pragma unroll
        for (int ni = 0; ni < 4; ++ni) {
            const int n = wn * 64 + ni * 16 + lr;          // W row = out col
            bf16x8 bf = *(const bf16x8*)(Wb + (size_t)n * 512 + kk + lk * 8);  // L2-hit
            acc[ni] = __builtin_amdgcn_mfma_f32_16x16x32_bf16(af, bf, acc[ni], 0, 0, 0);
        }
    }

    // epilogue: C/D layout col=lane&15, row=(lane>>4)*4+j  [verified m89]
    #pragma unroll
    for (int ni = 0; ni < 4; ++ni) {
        const int col = wn * 64 + ni * 16 + lr;
        const float bv = bias[col];
        #pragma unroll
        for (int j = 0; j < 4; ++j) {
            const int rowg = blockIdx.x * NPB + lk * 4 + j;
            float v = acc[ni][j] + bv;
            v = v > 0.0f ? v : 0.0f;
            __builtin_nontemporal_store(v, out + (size_t)rowg * D_OUT + col);
        }
    }
}

// ---------------- launch ----------------
extern "C" void kernel_launch(void* const* d_in, const int* in_sizes, int n_in,
                              void* d_out, int out_size, void* d_ws, size_t ws_size,
                              hipStream_t stream) {
    (void)in_sizes; (void)n_in; (void)out_size; (void)ws_size;
    const float* x   = (const float*)d_in[0];
    const float* adj = (const float*)d_in[1];
    const float* W   = (const float*)d_in[2];
    const float* b   = (const float*)d_in[3];

    unsigned short* Wb = (unsigned short*)d_ws;    // 256 KB bf16 W
    float* out = (float*)d_out;

    hipLaunchKernelGGL(k_convw, dim3(128), dim3(256), 0, stream, W, Wb);
    hipLaunchKernelGGL(k_fused, dim3(N_NODES / NPB), dim3(256), 0, stream,
                       x, adj, Wb, b, out);
}

// Round 11
// 217.898 us; speedup vs baseline: 1.1095x; 1.1095x over previous
//
#include <hip/hip_runtime.h>
#include <hip/hip_bf16.h>
#include <stdint.h>

// ---------------- problem constants ----------------
#define N_NODES 16384
#define D_IN    256
#define D_OUT   256
#define K_SAMP  10
#define HALF_FLAT (1u << 27)

// JAX PRNG mode: 1 = jax_threefry_partitionable (verified correct R3-R10).
#define JAX_PARTITIONABLE 1

typedef __attribute__((ext_vector_type(4))) float  f32x4;
typedef __attribute__((ext_vector_type(8))) short  bf16x8;
typedef __attribute__((ext_vector_type(4))) int    i32x4;

__device__ __forceinline__ uint32_t rotl32(uint32_t x, int r) {
    return (x << r) | (x >> (32 - r));
}

// Exact replica of jax threefry2x32 noise bits for flat index i = r*16384 + c, key (0,42).
__device__ __forceinline__ uint32_t jax_noise_bits(uint32_t r, uint32_t c) {
    const uint32_t i  = (r << 14) | c;
    const uint32_t k0 = 0u, k1 = 42u;
    const uint32_t k2 = 42u ^ 0x1BD11BDAu;
    uint32_t x0, x1;
#if JAX_PARTITIONABLE
    x0 = 0u;
    x1 = i;
#else
    const bool lo = (i < HALF_FLAT);
    x0 = lo ? i : (i - HALF_FLAT);
    x1 = lo ? (i + HALF_FLAT) : i;
#endif
    x0 += k0; x1 += k1;
#define TFR4(a,b,cc,d) \
    x0 += x1; x1 = rotl32(x1,a);  x1 ^= x0; \
    x0 += x1; x1 = rotl32(x1,b);  x1 ^= x0; \
    x0 += x1; x1 = rotl32(x1,cc); x1 ^= x0; \
    x0 += x1; x1 = rotl32(x1,d);  x1 ^= x0;
    TFR4(13,15,26,6);   x0 += k1; x1 += k2 + 1u;
    TFR4(17,29,16,24);  x0 += k2; x1 += k0 + 2u;
    TFR4(13,15,26,6);   x0 += k0; x1 += k1 + 3u;
    TFR4(17,29,16,24);  x0 += k1; x1 += k2 + 4u;
    TFR4(13,15,26,6);   x0 += k2; x1 += k0 + 5u;
#undef TFR4
#if JAX_PARTITIONABLE
    return x0 ^ x1;
#else
    return (i < HALF_FLAT) ? x0 : x1;
#endif
}

__device__ __forceinline__ unsigned short f2bfbits(float f) {
    __hip_bfloat16 h = __float2bfloat16(f);
    return *(unsigned short*)&h;
}

// pack 8 f32 -> 8 bf16 (as i32x4), same rounding as f2bfbits everywhere
__device__ __forceinline__ i32x4 cvt8bf(f32x4 a, f32x4 b) {
    i32x4 r;
    r[0] = (int)((uint32_t)f2bfbits(a[0]) | ((uint32_t)f2bfbits(a[1]) << 16));
    r[1] = (int)((uint32_t)f2bfbits(a[2]) | ((uint32_t)f2bfbits(a[3]) << 16));
    r[2] = (int)((uint32_t)f2bfbits(b[0]) | ((uint32_t)f2bfbits(b[1]) << 16));
    r[3] = (int)((uint32_t)f2bfbits(b[2]) | ((uint32_t)f2bfbits(b[3]) << 16));
    return r;
}

// ---------------- kernel 1: wave-per-node sample + aggregate → h=[x|agg] bf16 ------------
// 4 waves/block, each wave owns one node; fully wave-local (no barriers).
// nt-stream adjacency, integer fast path (adj is exactly 0.0/1.0), ballot compaction,
// dense threefry (≤2 evals/lane), register top-10 via wave-argmax, coalesced gathers.
__global__ __launch_bounds__(256) void k_agg(
    const float* __restrict__ x, const float* __restrict__ adj,
    unsigned short* __restrict__ h)
{
    const int t    = threadIdx.x;
    const int lane = t & 63;
    const int w    = t >> 6;
    const int r    = blockIdx.x * 4 + w;

    __shared__ unsigned short candc[4][128];   // per-wave nonzero-column list

    // ---- stream + compact (nt loads, integer fast path) ----
    const i32x4* rowp = (const i32x4*)(adj + (size_t)r * N_NODES);
    int nc = 0;                                 // wave-uniform candidate count
    #pragma unroll 8
    for (int it = 0; it < 64; ++it) {
        i32x4 v = __builtin_nontemporal_load(rowp + it * 64 + lane);
        uint32_t any = (uint32_t)v[0] | (uint32_t)v[1] | (uint32_t)v[2] | (uint32_t)v[3];
        if (__ballot(any != 0u)) {
            int cb = (it * 64 + lane) * 4;
            #pragma unroll
            for (int j = 0; j < 4; ++j) {
                unsigned long long mask = __ballot(v[j] != 0);
                if (mask) {
                    if (v[j] != 0) {
                        int below = __builtin_amdgcn_mbcnt_hi(
                            (uint32_t)(mask >> 32),
                            __builtin_amdgcn_mbcnt_lo((uint32_t)mask, 0));
                        int slot = nc + below;
                        if (slot < 128) candc[w][slot] = (unsigned short)(cb + j);
                    }
                    nc += __popcll(mask);
                }
            }
        }
    }
    if (nc > 128) nc = 128;                     // P(deg>128) ~ 0 (17 sigma)
    // no barrier: candc[w] is wave-private; ds ordering within wave via lgkmcnt
    // (pattern validated in R9/R10 phase A)

    // hoist self row load (hides under selection)
    f32x4 sv = *(const f32x4*)(x + (size_t)r * D_IN + lane * 4);

    // ---- dense threefry: keys for candidates lane and lane+64 ----
    unsigned long long k0 = 0ull, k1 = 0ull;
    if (lane < nc) {
        uint32_t c   = candc[w][lane];
        uint32_t u23 = jax_noise_bits((uint32_t)r, c) >> 9;   // monotone with uniform float
        k0 = ((((unsigned long long)u23) << 14) | (unsigned long long)(16383u - c)) + 1ull;
    }
    if (64 + lane < nc) {
        uint32_t c   = candc[w][64 + lane];
        uint32_t u23 = jax_noise_bits((uint32_t)r, c) >> 9;
        k1 = ((((unsigned long long)u23) << 14) | (unsigned long long)(16383u - c)) + 1ull;
    }

    // ---- top-K selection (register space) + gather ----
    const int m = nc < K_SAMP ? nc : K_SAMP;
    f32x4 acc = {0.f, 0.f, 0.f, 0.f};
    for (int s = 0; s < m; ++s) {
        unsigned long long my = k0 > k1 ? k0 : k1;
        #pragma unroll
        for (int o = 1; o < 64; o <<= 1) {
            unsigned long long other = __shfl_xor(my, o);
            if (other > my) my = other;
        }
        // keys unique (low 14 bits = distinct column) -> exactly one lane/slot matches
        if (k0 == my) k0 = 0ull; else if (k1 == my) k1 = 0ull;
        const int col = 16383 - (int)((my - 1ull) & 0x3FFFull);
        f32x4 xv = *(const f32x4*)(x + (size_t)col * D_IN + lane * 4);
        acc += xv;
    }
    const float inv = (m > 0) ? 1.0f / (float)m : 0.0f;

    // ---- write h row: [self | agg] bf16 ----
    ushort4 us, ua;
    us.x = f2bfbits(sv[0]);        us.y = f2bfbits(sv[1]);
    us.z = f2bfbits(sv[2]);        us.w = f2bfbits(sv[3]);
    ua.x = f2bfbits(acc[0] * inv); ua.y = f2bfbits(acc[1] * inv);
    ua.z = f2bfbits(acc[2] * inv); ua.w = f2bfbits(acc[3] * inv);
    unsigned short* hr = h + (size_t)r * (2 * D_IN);
    *(ushort4*)(hr + lane * 4)         = us;
    *(ushort4*)(hr + D_IN + lane * 4)  = ua;
}

// ---------------- kernel 2: out = relu(h @ W^T + b), MFMA bf16, f32 out ----------------
// BM=64, BN=64, BK=64 → 1024 blocks (4/CU). Double-buffered LDS, single barrier per
// K-step (issue loads(t+1) → compute(t) → ds_write(t+1) → barrier). Verified R6/R8.
// B is staged DIRECTLY from f32 W with in-register bf16 conversion (same rounding as
// the old k_convw) — convw kernel deleted. h loads non-temporal (read-once).
#define BM 64
#define BN 64
#define BK 64

__global__ __launch_bounds__(256) void k_gemm(
    const unsigned short* __restrict__ h, const float* __restrict__ W,
    const float* __restrict__ bias, float* __restrict__ out)
{
    __shared__ short As[2][BM * BK];   // rows XOR-swizzled: byte ^= (row&7)<<4
    __shared__ short Bs[2][BN * BK];

    const int t    = threadIdx.x;
    const int lane = t & 63;
    const int wv   = t >> 6;
    const int wr   = wv >> 1;      // wave row 0..1 (32 rows each)
    const int wc   = wv & 1;       // wave col 0..1 (32 cols each)
    const int m0   = blockIdx.x * BM;
    const int n0   = blockIdx.y * BN;
    const int lr   = lane & 15;
    const int lk   = lane >> 4;

    f32x4 acc[2][2] = {};

    const short* hA = (const short*)h;

    const int q0  = t, q1 = t + 256;
    const int r0  = q0 >> 3, c0 = q0 & 7;
    const int r1  = q1 >> 3, c1 = q1 & 7;
    const int ba0 = (r0 * 128 + c0 * 16) ^ ((r0 & 7) << 4);
    const int ba1 = (r1 * 128 + c1 * 16) ^ ((r1 & 7) << 4);

    {
        i32x4 a0 = __builtin_nontemporal_load(
            (const i32x4*)(hA + (size_t)(m0 + r0) * 512 + c0 * 8));
        i32x4 a1 = __builtin_nontemporal_load(
            (const i32x4*)(hA + (size_t)(m0 + r1) * 512 + c1 * 8));
        f32x4 w0a = *(const f32x4*)(W + (size_t)(n0 + r0) * 512 + c0 * 8);
        f32x4 w0b = *(const f32x4*)(W + (size_t)(n0 + r0) * 512 + c0 * 8 + 4);
        f32x4 w1a = *(const f32x4*)(W + (size_t)(n0 + r1) * 512 + c1 * 8);
        f32x4 w1b = *(const f32x4*)(W + (size_t)(n0 + r1) * 512 + c1 * 8 + 4);
        *(i32x4*)((char*)&As[0][0] + ba0) = a0;
        *(i32x4*)((char*)&As[0][0] + ba1) = a1;
        *(i32x4*)((char*)&Bs[0][0] + ba0) = cvt8bf(w0a, w0b);
        *(i32x4*)((char*)&Bs[0][0] + ba1) = cvt8bf(w1a, w1b);
    }
    __syncthreads();

    for (int tt = 0; tt < 8; ++tt) {
        const int cur = tt & 1;
        i32x4 a0, a1;
        f32x4 w0a, w0b, w1a, w1b;
        if (tt < 7) {
            const int k0n = (tt + 1) * BK;
            a0 = __builtin_nontemporal_load(
                (const i32x4*)(hA + (size_t)(m0 + r0) * 512 + k0n + c0 * 8));
            a1 = __builtin_nontemporal_load(
                (const i32x4*)(hA + (size_t)(m0 + r1) * 512 + k0n + c1 * 8));
            w0a = *(const f32x4*)(W + (size_t)(n0 + r0) * 512 + k0n + c0 * 8);
            w0b = *(const f32x4*)(W + (size_t)(n0 + r0) * 512 + k0n + c0 * 8 + 4);
            w1a = *(const f32x4*)(W + (size_t)(n0 + r1) * 512 + k0n + c1 * 8);
            w1b = *(const f32x4*)(W + (size_t)(n0 + r1) * 512 + k0n + c1 * 8 + 4);
        }

        #pragma unroll
        for (int kk = 0; kk < BK; kk += 32) {
            bf16x8 af[2], bf[2];
            #pragma unroll
            for (int mi = 0; mi < 2; ++mi) {
                int row = wr * 32 + mi * 16 + lr;
                int ba = (row * 128 + (kk + lk * 8) * 2) ^ ((row & 7) << 4);
                af[mi] = *(const bf16x8*)((const char*)&As[cur][0] + ba);
            }
            #pragma unroll
            for (int ni = 0; ni < 2; ++ni) {
                int row = wc * 32 + ni * 16 + lr;
                int ba = (row * 128 + (kk + lk * 8) * 2) ^ ((row & 7) << 4);
                bf[ni] = *(const bf16x8*)((const char*)&Bs[cur][0] + ba);
            }
            #pragma unroll
            for (int mi = 0; mi < 2; ++mi)
                #pragma unroll
                for (int ni = 0; ni < 2; ++ni)
                    acc[mi][ni] = __builtin_amdgcn_mfma_f32_16x16x32_bf16(
                        af[mi], bf[ni], acc[mi][ni], 0, 0, 0);
        }

        if (tt < 7) {
            const int nxt = cur ^ 1;
            *(i32x4*)((char*)&As[nxt][0] + ba0) = a0;
            *(i32x4*)((char*)&As[nxt][0] + ba1) = a1;
            *(i32x4*)((char*)&Bs[nxt][0] + ba0) = cvt8bf(w0a, w0b);
            *(i32x4*)((char*)&Bs[nxt][0] + ba1) = cvt8bf(w1a, w1b);
        }
        __syncthreads();
    }

    // epilogue: C/D layout col=lane&15, row=(lane>>4)*4+j  [verified m89]
    #pragma unroll
    for (int mi = 0; mi < 2; ++mi) {
        #pragma unroll
        for (int ni = 0; ni < 2; ++ni) {
            int col = n0 + wc * 32 + ni * 16 + lr;
            float bv = bias[col];
            #pragma unroll
            for (int j = 0; j < 4; ++j) {
                int rowg = m0 + wr * 32 + mi * 16 + lk * 4 + j;
                float v = acc[mi][ni][j] + bv;
                v = v > 0.0f ? v : 0.0f;
                __builtin_nontemporal_store(v, out + (size_t)rowg * D_OUT + col);
            }
        }
    }
}

// ---------------- launch ----------------
extern "C" void kernel_launch(void* const* d_in, const int* in_sizes, int n_in,
                              void* d_out, int out_size, void* d_ws, size_t ws_size,
                              hipStream_t stream) {
    (void)in_sizes; (void)n_in; (void)out_size; (void)ws_size;
    const float* x   = (const float*)d_in[0];
    const float* adj = (const float*)d_in[1];
    const float* W   = (const float*)d_in[2];
    const float* b   = (const float*)d_in[3];

    unsigned short* hbuf = (unsigned short*)d_ws;   // 16.8 MB bf16 h
    float* out = (float*)d_out;

    hipLaunchKernelGGL(k_agg,  dim3(N_NODES / 4), dim3(256), 0, stream, x, adj, hbuf);
    hipLaunchKernelGGL(k_gemm, dim3(N_NODES / BM, D_OUT / BN), dim3(256), 0, stream,
                       hbuf, W, b, out);
}

// Round 12
// 217.281 us; speedup vs baseline: 1.1126x; 1.0028x over previous
//
#include <hip/hip_runtime.h>
#include <hip/hip_bf16.h>
#include <stdint.h>

// ---------------- problem constants ----------------
#define N_NODES 16384
#define D_IN    256
#define D_OUT   256
#define K_SAMP  10
#define HALF_FLAT (1u << 27)

// JAX PRNG mode: 1 = jax_threefry_partitionable (verified correct R3-R11).
#define JAX_PARTITIONABLE 1

typedef __attribute__((ext_vector_type(4))) float  f32x4;
typedef __attribute__((ext_vector_type(8))) short  bf16x8;
typedef __attribute__((ext_vector_type(4))) int    i32x4;

__device__ __forceinline__ uint32_t rotl32(uint32_t x, int r) {
    return (x << r) | (x >> (32 - r));
}

// Exact replica of jax threefry2x32 noise bits for flat index i = r*16384 + c, key (0,42).
__device__ __forceinline__ uint32_t jax_noise_bits(uint32_t r, uint32_t c) {
    const uint32_t i  = (r << 14) | c;
    const uint32_t k0 = 0u, k1 = 42u;
    const uint32_t k2 = 42u ^ 0x1BD11BDAu;
    uint32_t x0, x1;
#if JAX_PARTITIONABLE
    x0 = 0u;
    x1 = i;
#else
    const bool lo = (i < HALF_FLAT);
    x0 = lo ? i : (i - HALF_FLAT);
    x1 = lo ? (i + HALF_FLAT) : i;
#endif
    x0 += k0; x1 += k1;
#define TFR4(a,b,cc,d) \
    x0 += x1; x1 = rotl32(x1,a);  x1 ^= x0; \
    x0 += x1; x1 = rotl32(x1,b);  x1 ^= x0; \
    x0 += x1; x1 = rotl32(x1,cc); x1 ^= x0; \
    x0 += x1; x1 = rotl32(x1,d);  x1 ^= x0;
    TFR4(13,15,26,6);   x0 += k1; x1 += k2 + 1u;
    TFR4(17,29,16,24);  x0 += k2; x1 += k0 + 2u;
    TFR4(13,15,26,6);   x0 += k0; x1 += k1 + 3u;
    TFR4(17,29,16,24);  x0 += k1; x1 += k2 + 4u;
    TFR4(13,15,26,6);   x0 += k2; x1 += k0 + 5u;
#undef TFR4
#if JAX_PARTITIONABLE
    return x0 ^ x1;
#else
    return (i < HALF_FLAT) ? x0 : x1;
#endif
}

__device__ __forceinline__ unsigned short f2bfbits(float f) {
    __hip_bfloat16 h = __float2bfloat16(f);
    return *(unsigned short*)&h;
}

// pack 8 f32 -> 8 bf16 (as i32x4), same rounding as f2bfbits everywhere
__device__ __forceinline__ i32x4 cvt8bf(f32x4 a, f32x4 b) {
    i32x4 r;
    r[0] = (int)((uint32_t)f2bfbits(a[0]) | ((uint32_t)f2bfbits(a[1]) << 16));
    r[1] = (int)((uint32_t)f2bfbits(a[2]) | ((uint32_t)f2bfbits(a[3]) << 16));
    r[2] = (int)((uint32_t)f2bfbits(b[0]) | ((uint32_t)f2bfbits(b[1]) << 16));
    r[3] = (int)((uint32_t)f2bfbits(b[2]) | ((uint32_t)f2bfbits(b[3]) << 16));
    return r;
}

// ---------------- kernel 1: wave-per-node sample + aggregate → h=[x|agg] bf16 ------------
// 4 waves/block, each wave owns one node; fully wave-local (no barriers).
// __launch_bounds__(256,8): force VGPR<=64 so 8 blocks/CU (32 waves) stream concurrently.
// unroll 4 (was 8) to fit the register budget without spills.
__global__ __launch_bounds__(256, 8) void k_agg(
    const float* __restrict__ x, const float* __restrict__ adj,
    unsigned short* __restrict__ h)
{
    const int t    = threadIdx.x;
    const int lane = t & 63;
    const int w    = t >> 6;
    const int r    = blockIdx.x * 4 + w;

    __shared__ unsigned short candc[4][128];   // per-wave nonzero-column list

    // ---- stream + compact (nt loads, integer fast path: adj is exactly 0.0/1.0) ----
    const i32x4* rowp = (const i32x4*)(adj + (size_t)r * N_NODES);
    int nc = 0;                                 // wave-uniform candidate count
    #pragma unroll 4
    for (int it = 0; it < 64; ++it) {
        i32x4 v = __builtin_nontemporal_load(rowp + it * 64 + lane);
        uint32_t any = (uint32_t)v[0] | (uint32_t)v[1] | (uint32_t)v[2] | (uint32_t)v[3];
        if (__ballot(any != 0u)) {
            int cb = (it * 64 + lane) * 4;
            #pragma unroll
            for (int j = 0; j < 4; ++j) {
                unsigned long long mask = __ballot(v[j] != 0);
                if (mask) {
                    if (v[j] != 0) {
                        int below = __builtin_amdgcn_mbcnt_hi(
                            (uint32_t)(mask >> 32),
                            __builtin_amdgcn_mbcnt_lo((uint32_t)mask, 0));
                        int slot = nc + below;
                        if (slot < 128) candc[w][slot] = (unsigned short)(cb + j);
                    }
                    nc += __popcll(mask);
                }
            }
        }
    }
    if (nc > 128) nc = 128;                     // P(deg>128) ~ 0 (17 sigma)
    // no barrier: candc[w] is wave-private; within-wave ds ordering via lgkmcnt
    // (validated R9/R10/R11)

    // hoist self row load (hides under selection)
    f32x4 sv = *(const f32x4*)(x + (size_t)r * D_IN + lane * 4);

    // ---- dense threefry: keys for candidates lane and lane+64 ----
    unsigned long long k0 = 0ull, k1 = 0ull;
    if (lane < nc) {
        uint32_t c   = candc[w][lane];
        uint32_t u23 = jax_noise_bits((uint32_t)r, c) >> 9;   // monotone with uniform float
        k0 = ((((unsigned long long)u23) << 14) | (unsigned long long)(16383u - c)) + 1ull;
    }
    if (64 + lane < nc) {
        uint32_t c   = candc[w][64 + lane];
        uint32_t u23 = jax_noise_bits((uint32_t)r, c) >> 9;
        k1 = ((((unsigned long long)u23) << 14) | (unsigned long long)(16383u - c)) + 1ull;
    }

    // ---- top-K selection (register space) + gather ----
    const int m = nc < K_SAMP ? nc : K_SAMP;
    f32x4 acc = {0.f, 0.f, 0.f, 0.f};
    for (int s = 0; s < m; ++s) {
        unsigned long long my = k0 > k1 ? k0 : k1;
        #pragma unroll
        for (int o = 1; o < 64; o <<= 1) {
            unsigned long long other = __shfl_xor(my, o);
            if (other > my) my = other;
        }
        // keys unique (low 14 bits = distinct column) -> exactly one lane/slot matches
        if (k0 == my) k0 = 0ull; else if (k1 == my) k1 = 0ull;
        const int col = 16383 - (int)((my - 1ull) & 0x3FFFull);
        f32x4 xv = *(const f32x4*)(x + (size_t)col * D_IN + lane * 4);
        acc += xv;
    }
    const float inv = (m > 0) ? 1.0f / (float)m : 0.0f;

    // ---- write h row: [self | agg] bf16 ----
    ushort4 us, ua;
    us.x = f2bfbits(sv[0]);        us.y = f2bfbits(sv[1]);
    us.z = f2bfbits(sv[2]);        us.w = f2bfbits(sv[3]);
    ua.x = f2bfbits(acc[0] * inv); ua.y = f2bfbits(acc[1] * inv);
    ua.z = f2bfbits(acc[2] * inv); ua.w = f2bfbits(acc[3] * inv);
    unsigned short* hr = h + (size_t)r * (2 * D_IN);
    *(ushort4*)(hr + lane * 4)         = us;
    *(ushort4*)(hr + D_IN + lane * 4)  = ua;
}

// ---------------- kernel 2: out = relu(h @ W^T + b), MFMA bf16, f32 out ----------------
// BM=64, BN=32 → 2048 blocks (8/CU), LDS 24KB. Double-buffered, single barrier per
// K-step. B staged from f32 W with in-register bf16 cvt (same rounding as ref path).
// h loads REGULAR (L2-resident, just produced); out stores non-temporal.
#define BM 64
#define BN 32
#define BK 64

__global__ __launch_bounds__(256, 8) void k_gemm(
    const unsigned short* __restrict__ h, const float* __restrict__ W,
    const float* __restrict__ bias, float* __restrict__ out)
{
    __shared__ short As[2][BM * BK];   // 8KB/buf, rows XOR-swizzled: byte ^= (row&7)<<4
    __shared__ short Bs[2][BN * BK];   // 4KB/buf

    const int t    = threadIdx.x;
    const int lane = t & 63;
    const int wv   = t >> 6;
    const int wr   = wv >> 1;      // wave row 0..1 (32 rows each)
    const int wc   = wv & 1;       // wave col 0..1 (16 cols each)
    const int m0   = blockIdx.x * BM;
    const int n0   = blockIdx.y * BN;
    const int lr   = lane & 15;
    const int lk   = lane >> 4;

    f32x4 acc[2] = {};             // 2 m-frags x 1 n-frag

    const short* hA = (const short*)h;

    // A staging: 512 chunks of 16B, 2/thread; B staging: 256 chunks, 1/thread
    const int q0  = t, q1 = t + 256;
    const int ar0 = q0 >> 3, ac0 = q0 & 7;
    const int ar1 = q1 >> 3, ac1 = q1 & 7;
    const int aba0 = (ar0 * 128 + ac0 * 16) ^ ((ar0 & 7) << 4);
    const int aba1 = (ar1 * 128 + ac1 * 16) ^ ((ar1 & 7) << 4);
    const int br0 = t >> 3, bc0 = t & 7;
    const int bba0 = (br0 * 128 + bc0 * 16) ^ ((br0 & 7) << 4);

    {
        i32x4 a0 = *(const i32x4*)(hA + (size_t)(m0 + ar0) * 512 + ac0 * 8);
        i32x4 a1 = *(const i32x4*)(hA + (size_t)(m0 + ar1) * 512 + ac1 * 8);
        f32x4 wa = *(const f32x4*)(W + (size_t)(n0 + br0) * 512 + bc0 * 8);
        f32x4 wb = *(const f32x4*)(W + (size_t)(n0 + br0) * 512 + bc0 * 8 + 4);
        *(i32x4*)((char*)&As[0][0] + aba0) = a0;
        *(i32x4*)((char*)&As[0][0] + aba1) = a1;
        *(i32x4*)((char*)&Bs[0][0] + bba0) = cvt8bf(wa, wb);
    }
    __syncthreads();

    for (int tt = 0; tt < 8; ++tt) {
        const int cur = tt & 1;
        i32x4 a0, a1;
        f32x4 wa, wb;
        if (tt < 7) {
            const int k0n = (tt + 1) * BK;
            a0 = *(const i32x4*)(hA + (size_t)(m0 + ar0) * 512 + k0n + ac0 * 8);
            a1 = *(const i32x4*)(hA + (size_t)(m0 + ar1) * 512 + k0n + ac1 * 8);
            wa = *(const f32x4*)(W + (size_t)(n0 + br0) * 512 + k0n + bc0 * 8);
            wb = *(const f32x4*)(W + (size_t)(n0 + br0) * 512 + k0n + bc0 * 8 + 4);
        }

        #pragma unroll
        for (int kk = 0; kk < BK; kk += 32) {
            bf16x8 af[2], bf;
            #pragma unroll
            for (int mi = 0; mi < 2; ++mi) {
                int row = wr * 32 + mi * 16 + lr;
                int ba = (row * 128 + (kk + lk * 8) * 2) ^ ((row & 7) << 4);
                af[mi] = *(const bf16x8*)((const char*)&As[cur][0] + ba);
            }
            {
                int row = wc * 16 + lr;
                int ba = (row * 128 + (kk + lk * 8) * 2) ^ ((row & 7) << 4);
                bf = *(const bf16x8*)((const char*)&Bs[cur][0] + ba);
            }
            #pragma unroll
            for (int mi = 0; mi < 2; ++mi)
                acc[mi] = __builtin_amdgcn_mfma_f32_16x16x32_bf16(af[mi], bf, acc[mi], 0, 0, 0);
        }

        if (tt < 7) {
            const int nxt = cur ^ 1;
            *(i32x4*)((char*)&As[nxt][0] + aba0) = a0;
            *(i32x4*)((char*)&As[nxt][0] + aba1) = a1;
            *(i32x4*)((char*)&Bs[nxt][0] + bba0) = cvt8bf(wa, wb);
        }
        __syncthreads();
    }

    // epilogue: C/D layout col=lane&15, row=(lane>>4)*4+j  [verified m89]
    #pragma unroll
    for (int mi = 0; mi < 2; ++mi) {
        int col = n0 + wc * 16 + lr;
        float bv = bias[col];
        #pragma unroll
        for (int j = 0; j < 4; ++j) {
            int rowg = m0 + wr * 32 + mi * 16 + lk * 4 + j;
            float v = acc[mi][j] + bv;
            v = v > 0.0f ? v : 0.0f;
            __builtin_nontemporal_store(v, out + (size_t)rowg * D_OUT + col);
        }
    }
}

// ---------------- launch ----------------
extern "C" void kernel_launch(void* const* d_in, const int* in_sizes, int n_in,
                              void* d_out, int out_size, void* d_ws, size_t ws_size,
                              hipStream_t stream) {
    (void)in_sizes; (void)n_in; (void)out_size; (void)ws_size;
    const float* x   = (const float*)d_in[0];
    const float* adj = (const float*)d_in[1];
    const float* W   = (const float*)d_in[2];
    const float* b   = (const float*)d_in[3];

    unsigned short* hbuf = (unsigned short*)d_ws;   // 16.8 MB bf16 h
    float* out = (float*)d_out;

    hipLaunchKernelGGL(k_agg,  dim3(N_NODES / 4), dim3(256), 0, stream, x, adj, hbuf);
    hipLaunchKernelGGL(k_gemm, dim3(N_NODES / BM, D_OUT / BN), dim3(256), 0, stream,
                       hbuf, W, b, out);
}

// Round 13
// 211.159 us; speedup vs baseline: 1.1449x; 1.0290x over previous
//
#include <hip/hip_runtime.h>
#include <hip/hip_bf16.h>
#include <stdint.h>

// ---------------- problem constants ----------------
#define N_NODES 16384
#define D_IN    256
#define D_OUT   256
#define K_SAMP  10
#define HALF_FLAT (1u << 27)

// JAX PRNG mode: 1 = jax_threefry_partitionable (verified correct R3-R12).
#define JAX_PARTITIONABLE 1

typedef __attribute__((ext_vector_type(4))) float  f32x4;
typedef __attribute__((ext_vector_type(8))) short  bf16x8;
typedef __attribute__((ext_vector_type(4))) int    i32x4;

__device__ __forceinline__ uint32_t rotl32(uint32_t x, int r) {
    return (x << r) | (x >> (32 - r));
}

// Exact replica of jax threefry2x32 noise bits for flat index i = r*16384 + c, key (0,42).
__device__ __forceinline__ uint32_t jax_noise_bits(uint32_t r, uint32_t c) {
    const uint32_t i  = (r << 14) | c;
    const uint32_t k0 = 0u, k1 = 42u;
    const uint32_t k2 = 42u ^ 0x1BD11BDAu;
    uint32_t x0, x1;
#if JAX_PARTITIONABLE
    x0 = 0u;
    x1 = i;
#else
    const bool lo = (i < HALF_FLAT);
    x0 = lo ? i : (i - HALF_FLAT);
    x1 = lo ? (i + HALF_FLAT) : i;
#endif
    x0 += k0; x1 += k1;
#define TFR4(a,b,cc,d) \
    x0 += x1; x1 = rotl32(x1,a);  x1 ^= x0; \
    x0 += x1; x1 = rotl32(x1,b);  x1 ^= x0; \
    x0 += x1; x1 = rotl32(x1,cc); x1 ^= x0; \
    x0 += x1; x1 = rotl32(x1,d);  x1 ^= x0;
    TFR4(13,15,26,6);   x0 += k1; x1 += k2 + 1u;
    TFR4(17,29,16,24);  x0 += k2; x1 += k0 + 2u;
    TFR4(13,15,26,6);   x0 += k0; x1 += k1 + 3u;
    TFR4(17,29,16,24);  x0 += k1; x1 += k2 + 4u;
    TFR4(13,15,26,6);   x0 += k2; x1 += k0 + 5u;
#undef TFR4
#if JAX_PARTITIONABLE
    return x0 ^ x1;
#else
    return (i < HALF_FLAT) ? x0 : x1;
#endif
}

__device__ __forceinline__ unsigned short f2bfbits(float f) {
    __hip_bfloat16 h = __float2bfloat16(f);
    return *(unsigned short*)&h;
}

// ---------------- kernel 1: wave-per-node sample + aggregate → h=[x|agg] bf16 ------------
// R8-exact configuration (measured best): 4 waves/block, wave owns one node, nt-stream
// adjacency with integer fast path, ballot compaction, dense threefry, register top-10.
// Tweaks validated in later passing rounds: no barrier (candc wave-private), hoisted
// self-row load. Blocks 0..127 additionally convert W f32 -> Wb bf16 (replaces k_convw).
__global__ __launch_bounds__(256) void k_agg(
    const float* __restrict__ x, const float* __restrict__ adj,
    const float* __restrict__ W, unsigned short* __restrict__ Wb,
    unsigned short* __restrict__ h)
{
    const int t    = threadIdx.x;
    const int lane = t & 63;
    const int w    = t >> 6;
    const int r    = blockIdx.x * 4 + w;

    // fold of k_convw: 128 blocks x 256 threads x 4 floats = 131072 = all of W
    if (blockIdx.x < 128) {
        int i = (blockIdx.x * 256 + t) * 4;
        f32x4 v = *(const f32x4*)(W + i);
        ushort4 u;
        u.x = f2bfbits(v[0]); u.y = f2bfbits(v[1]);
        u.z = f2bfbits(v[2]); u.w = f2bfbits(v[3]);
        *(ushort4*)(Wb + i) = u;
    }

    __shared__ unsigned short candc[4][128];   // per-wave nonzero-column list

    // ---- stream + compact (nt loads, integer fast path: adj is exactly 0.0/1.0) ----
    const i32x4* rowp = (const i32x4*)(adj + (size_t)r * N_NODES);
    int nc = 0;                                 // wave-uniform candidate count
    #pragma unroll 8
    for (int it = 0; it < 64; ++it) {
        i32x4 v = __builtin_nontemporal_load(rowp + it * 64 + lane);
        uint32_t any = (uint32_t)v[0] | (uint32_t)v[1] | (uint32_t)v[2] | (uint32_t)v[3];
        if (__ballot(any != 0u)) {
            int cb = (it * 64 + lane) * 4;
            #pragma unroll
            for (int j = 0; j < 4; ++j) {
                unsigned long long mask = __ballot(v[j] != 0);
                if (mask) {
                    if (v[j] != 0) {
                        int below = __builtin_amdgcn_mbcnt_hi(
                            (uint32_t)(mask >> 32),
                            __builtin_amdgcn_mbcnt_lo((uint32_t)mask, 0));
                        int slot = nc + below;
                        if (slot < 128) candc[w][slot] = (unsigned short)(cb + j);
                    }
                    nc += __popcll(mask);
                }
            }
        }
    }
    if (nc > 128) nc = 128;                     // P(deg>128) ~ 0 (17 sigma)
    // no barrier: candc[w] is wave-private; within-wave ds ordering via lgkmcnt
    // (validated R10/R11/R12)

    // hoist self row load (hides under selection; validated R11/R12)
    f32x4 sv = *(const f32x4*)(x + (size_t)r * D_IN + lane * 4);

    // ---- dense threefry: keys for candidates lane and lane+64 ----
    unsigned long long k0 = 0ull, k1 = 0ull;
    if (lane < nc) {
        uint32_t c   = candc[w][lane];
        uint32_t u23 = jax_noise_bits((uint32_t)r, c) >> 9;   // monotone with uniform float
        k0 = ((((unsigned long long)u23) << 14) | (unsigned long long)(16383u - c)) + 1ull;
    }
    if (64 + lane < nc) {
        uint32_t c   = candc[w][64 + lane];
        uint32_t u23 = jax_noise_bits((uint32_t)r, c) >> 9;
        k1 = ((((unsigned long long)u23) << 14) | (unsigned long long)(16383u - c)) + 1ull;
    }

    // ---- top-K selection (register space) + gather ----
    const int m = nc < K_SAMP ? nc : K_SAMP;
    f32x4 acc = {0.f, 0.f, 0.f, 0.f};
    for (int s = 0; s < m; ++s) {
        unsigned long long my = k0 > k1 ? k0 : k1;
        #pragma unroll
        for (int o = 1; o < 64; o <<= 1) {
            unsigned long long other = __shfl_xor(my, o);
            if (other > my) my = other;
        }
        // keys unique (low 14 bits = distinct column) -> exactly one lane/slot matches
        if (k0 == my) k0 = 0ull; else if (k1 == my) k1 = 0ull;
        const int col = 16383 - (int)((my - 1ull) & 0x3FFFull);
        f32x4 xv = *(const f32x4*)(x + (size_t)col * D_IN + lane * 4);
        acc += xv;
    }
    const float inv = (m > 0) ? 1.0f / (float)m : 0.0f;

    // ---- write h row: [self | agg] bf16 ----
    ushort4 us, ua;
    us.x = f2bfbits(sv[0]);        us.y = f2bfbits(sv[1]);
    us.z = f2bfbits(sv[2]);        us.w = f2bfbits(sv[3]);
    ua.x = f2bfbits(acc[0] * inv); ua.y = f2bfbits(acc[1] * inv);
    ua.z = f2bfbits(acc[2] * inv); ua.w = f2bfbits(acc[3] * inv);
    unsigned short* hr = h + (size_t)r * (2 * D_IN);
    *(ushort4*)(hr + lane * 4)         = us;
    *(ushort4*)(hr + D_IN + lane * 4)  = ua;
}

// ---------------- kernel 2: out = relu(h @ Wb^T + b), MFMA bf16, f32 out ----------------
// R8-exact: BM=64, BN=64, BK=64 → 1024 blocks (4/CU). Double-buffered LDS, single
// barrier per K-step (issue loads(t+1) → compute(t) → ds_write(t+1) → barrier).
// Only change: non-temporal out stores (write-once; validated R10-R12).
#define BM 64
#define BN 64
#define BK 64

__global__ __launch_bounds__(256) void k_gemm(
    const unsigned short* __restrict__ h, const unsigned short* __restrict__ Wb,
    const float* __restrict__ bias, float* __restrict__ out)
{
    __shared__ short As[2][BM * BK];   // rows XOR-swizzled: byte ^= (row&7)<<4
    __shared__ short Bs[2][BN * BK];

    const int t    = threadIdx.x;
    const int lane = t & 63;
    const int wv   = t >> 6;
    const int wr   = wv >> 1;      // wave row 0..1 (32 rows each)
    const int wc   = wv & 1;       // wave col 0..1 (32 cols each)
    const int m0   = blockIdx.x * BM;
    const int n0   = blockIdx.y * BN;
    const int lr   = lane & 15;
    const int lk   = lane >> 4;

    f32x4 acc[2][2] = {};

    const short* hA = (const short*)h;
    const short* wB = (const short*)Wb;

    const int q0  = t, q1 = t + 256;
    const int r0  = q0 >> 3, c0 = q0 & 7;
    const int r1  = q1 >> 3, c1 = q1 & 7;
    const int ba0 = (r0 * 128 + c0 * 16) ^ ((r0 & 7) << 4);
    const int ba1 = (r1 * 128 + c1 * 16) ^ ((r1 & 7) << 4);

    {
        i32x4 a0 = *(const i32x4*)(hA + (size_t)(m0 + r0) * 512 + c0 * 8);
        i32x4 a1 = *(const i32x4*)(hA + (size_t)(m0 + r1) * 512 + c1 * 8);
        i32x4 b0 = *(const i32x4*)(wB + (size_t)(n0 + r0) * 512 + c0 * 8);
        i32x4 b1 = *(const i32x4*)(wB + (size_t)(n0 + r1) * 512 + c1 * 8);
        *(i32x4*)((char*)&As[0][0] + ba0) = a0;
        *(i32x4*)((char*)&As[0][0] + ba1) = a1;
        *(i32x4*)((char*)&Bs[0][0] + ba0) = b0;
        *(i32x4*)((char*)&Bs[0][0] + ba1) = b1;
    }
    __syncthreads();

    for (int tt = 0; tt < 8; ++tt) {
        const int cur = tt & 1;
        i32x4 a0, a1, b0, b1;
        if (tt < 7) {
            const int k0n = (tt + 1) * BK;
            a0 = *(const i32x4*)(hA + (size_t)(m0 + r0) * 512 + k0n + c0 * 8);
            a1 = *(const i32x4*)(hA + (size_t)(m0 + r1) * 512 + k0n + c1 * 8);
            b0 = *(const i32x4*)(wB + (size_t)(n0 + r0) * 512 + k0n + c0 * 8);
            b1 = *(const i32x4*)(wB + (size_t)(n0 + r1) * 512 + k0n + c1 * 8);
        }

        #pragma unroll
        for (int kk = 0; kk < BK; kk += 32) {
            bf16x8 af[2], bf[2];
            #pragma unroll
            for (int mi = 0; mi < 2; ++mi) {
                int row = wr * 32 + mi * 16 + lr;
                int ba = (row * 128 + (kk + lk * 8) * 2) ^ ((row & 7) << 4);
                af[mi] = *(const bf16x8*)((const char*)&As[cur][0] + ba);
            }
            #pragma unroll
            for (int ni = 0; ni < 2; ++ni) {
                int row = wc * 32 + ni * 16 + lr;
                int ba = (row * 128 + (kk + lk * 8) * 2) ^ ((row & 7) << 4);
                bf[ni] = *(const bf16x8*)((const char*)&Bs[cur][0] + ba);
            }
            #pragma unroll
            for (int mi = 0; mi < 2; ++mi)
                #pragma unroll
                for (int ni = 0; ni < 2; ++ni)
                    acc[mi][ni] = __builtin_amdgcn_mfma_f32_16x16x32_bf16(
                        af[mi], bf[ni], acc[mi][ni], 0, 0, 0);
        }

        if (tt < 7) {
            const int nxt = cur ^ 1;
            *(i32x4*)((char*)&As[nxt][0] + ba0) = a0;
            *(i32x4*)((char*)&As[nxt][0] + ba1) = a1;
            *(i32x4*)((char*)&Bs[nxt][0] + ba0) = b0;
            *(i32x4*)((char*)&Bs[nxt][0] + ba1) = b1;
        }
        __syncthreads();
    }

    // epilogue: C/D layout col=lane&15, row=(lane>>4)*4+j  [verified m89]
    #pragma unroll
    for (int mi = 0; mi < 2; ++mi) {
        #pragma unroll
        for (int ni = 0; ni < 2; ++ni) {
            int col = n0 + wc * 32 + ni * 16 + lr;
            float bv = bias[col];
            #pragma unroll
            for (int j = 0; j < 4; ++j) {
                int rowg = m0 + wr * 32 + mi * 16 + lk * 4 + j;
                float v = acc[mi][ni][j] + bv;
                v = v > 0.0f ? v : 0.0f;
                __builtin_nontemporal_store(v, out + (size_t)rowg * D_OUT + col);
            }
        }
    }
}

// ---------------- launch ----------------
extern "C" void kernel_launch(void* const* d_in, const int* in_sizes, int n_in,
                              void* d_out, int out_size, void* d_ws, size_t ws_size,
                              hipStream_t stream) {
    (void)in_sizes; (void)n_in; (void)out_size; (void)ws_size;
    const float* x   = (const float*)d_in[0];
    const float* adj = (const float*)d_in[1];
    const float* W   = (const float*)d_in[2];
    const float* b   = (const float*)d_in[3];

    unsigned short* hbuf = (unsigned short*)d_ws;                                  // 16.8 MB
    unsigned short* Wb   = (unsigned short*)((char*)d_ws + (size_t)N_NODES * 512 * 2);
    float* out = (float*)d_out;

    hipLaunchKernelGGL(k_agg,  dim3(N_NODES / 4), dim3(256), 0, stream, x, adj, W, Wb, hbuf);
    hipLaunchKernelGGL(k_gemm, dim3(N_NODES / BM, D_OUT / BN), dim3(256), 0, stream,
                       hbuf, Wb, b, out);
}